// Round 12
// baseline (75.340 us; speedup 1.0000x reference)
//
#include <hip/hip_runtime.h>
#include <hip/hip_bf16.h>
#include <hip/hip_fp16.h>

// Problem constants (fixed by setup_inputs)
#define CIN      8
#define HH       100
#define WW       152
#define HWSZ     (HH * WW)          // 15200
#define OHGT     200
#define OWID     304
#define PPI      419                 // 169 body + 169 edge + 81 fused
#define OUT_PER_INST (OHGT * OWID)   // 60800

#define RSTRIP   5                   // interior logit rows per block (100 = 20*5)
#define TROWS    6                   // 5 interior + 1 halo
#define NSTRIPS  20
#define TILEPX   (TROWS * WW)        // 912 logit px per block = 57 chunks of 16
#define NCHUNK   57
#define P2ITEMS  (3 * RSTRIP * 76)   // 1140 upsample items per block

// Param layout (row of 419 floats):
//  body:  w1[8][10]@0  w2[8][8]@80  w3[8]@144  b1[8]@152 b2[8]@160 b3@168
//  edge:  same +169
//  fused: wf1[8][8]@338 wf2[8]@402 bf1[8]@410 bf2@418

typedef float    vf4   __attribute__((ext_vector_type(4)));
typedef float    f32x4 __attribute__((ext_vector_type(4)));
typedef _Float16 f16x8 __attribute__((ext_vector_type(8)));
typedef _Float16 f16x4 __attribute__((ext_vector_type(4)));

// mfma_f32_16x16x32_f16 fragment maps (gfx950, §3/§10; C/D m89-verified):
//   A: lane l -> M-row = l&15,  K = (l>>4)*8 + j   (j = half 0..7)
//   B: lane l -> N-col = l&15,  K = (l>>4)*8 + j
//   C/D: reg r, lane l -> row = (l>>4)*4 + r, col = l&15

__global__ __launch_bounds__(256) void dmh_mfma_kernel(
    const float* __restrict__ fbody,      // [2][8][H][W]
    const float* __restrict__ fedge,      // [2][8][H][W]
    const float* __restrict__ params,     // [n_inst][419]
    const float* __restrict__ locs,       // [n_inst][2]
    const float* __restrict__ soi_tab,    // [5]
    const int*   __restrict__ im_inds,    // [n_inst]
    const int*   __restrict__ fpn_levels, // [n_inst]
    float* __restrict__ out,              // [3][n_inst][200][304]
    int n_inst)
{
    const int s    = blockIdx.x;
    const int n    = blockIdx.y;
    const int tid  = threadIdx.x;
    const int r0   = RSTRIP * s;
    const int lane = tid & 63;
    const int wid  = tid >> 6;
    const int row  = lane & 15;          // M-row / px-col / N-col position
    const int g    = lane >> 4;          // k-group

    __shared__ float    slogf[3 * TILEPX];      // 10.9 KB logits
    __shared__ _Float16 scratch[4 * 512];       // 1 KB per wave: [px=16][k=32] f16

    _Float16* sc = scratch + wid * 512;

    // Zero own wave's scratch (finite-mask safety for padded K slots).
    #pragma unroll
    for (int z = 0; z < 8; ++z) sc[lane * 8 + z] = (_Float16)0.f;

    // Block-uniform instance scalars
    const float* __restrict__ p = params + (size_t)n * PPI;
    const int   im      = im_inds[n];
    const float inv_soi = 1.0f / soi_tab[fpn_levels[n]];
    const float sx = (locs[2 * n]     - 4.0f) * inv_soi;
    const float sy = (locs[2 * n + 1] - 4.0f) * inv_soi;
    const float k8 = 8.0f * inv_soi;
    const float* __restrict__ fb_base = fbody + (size_t)im * CIN * HWSZ;
    const float* __restrict__ fe_base = fedge + (size_t)im * CIN * HWSZ;

    // ---- A-fragments (all 5 weight matrices) + bias C-fragments: ONCE ----
    // mfma1: rows0-7 W1b@k0-9 | rows8-15 W1e@k10-19
    // mfma2: rows0-7 W2b@k0-7 | rows8-15 W2e@k8-15
    // mfma3: rows0-7 W1f@k0-7
    // mfma4: row0 w3b@k0-7, row1 w3e@k8-15, row2 wf2@k16-23
    f16x8 A1, A2, A3, A4;
    #pragma unroll
    for (int j = 0; j < 8; ++j) {
        const int k = g * 8 + j;
        float a1 = 0.f, a2 = 0.f, a3 = 0.f, a4 = 0.f;
        if (row < 8) {
            if (k < 10) a1 = p[row * 10 + k];
            if (k < 8)  { a2 = p[80 + row * 8 + k]; a3 = p[338 + row * 8 + k]; }
        } else {
            if (k >= 10 && k < 20) a1 = p[169 + (row - 8) * 10 + (k - 10)];
            if (k >= 8  && k < 16) a2 = p[169 + 80 + (row - 8) * 8 + (k - 8)];
        }
        if (row == 0 && k < 8)             a4 = p[144 + k];
        if (row == 1 && k >= 8  && k < 16) a4 = p[169 + 144 + (k - 8)];
        if (row == 2 && k >= 16 && k < 24) a4 = p[402 + (k - 16)];
        A1[j] = (_Float16)a1; A2[j] = (_Float16)a2;
        A3[j] = (_Float16)a3; A4[j] = (_Float16)a4;
    }
    f32x4 C1, C2, C3, C4;
    #pragma unroll
    for (int rI = 0; rI < 4; ++rI) {
        const int R = g * 4 + rI;
        C1[rI] = (R < 8) ? p[152 + R] : p[169 + 152 + (R - 8)];
        C2[rI] = (R < 8) ? p[160 + R] : p[169 + 160 + (R - 8)];
        C3[rI] = (R < 8) ? p[410 + R] : 0.f;
        C4[rI] = (R == 0) ? p[168] : (R == 1) ? p[169 + 168] : (R == 2) ? p[418] : 0.f;
    }

    // ---------------- Phase 1: 16-px chunks through the MFMA chain ----------------
    for (int ck = wid; ck < NCHUNK; ck += 4) {
        const int pxl = ck * 16 + row;          // 0..911 within tile
        const int rl  = pxl / WW;
        const int cc  = pxl - rl * WW;
        const int rr  = min(r0 + rl, HH - 1);   // halo clamp (edge-pad)
        const int gpx = rr * WW + cc;
        const float dxv = sx - (float)cc * k8;
        const float dyv = sy - (float)rr * k8;

        // Stage B1 = [dx,dy,fb0-7 @k0-9 | dx,dy,fe0-7 @k10-19 | *] into scratch[px][k]
        #pragma unroll
        for (int t = 0; t < 4; ++t) {
            const int chn = g + 4 * t;          // 0..15
            const float v = (chn < 8) ? fb_base[chn * HWSZ + gpx]
                                      : fe_base[(chn - 8) * HWSZ + gpx];
            const int k = (chn < 8) ? (2 + chn) : (4 + chn);
            sc[row * 32 + k] = (_Float16)v;
        }
        if (g == 0) { sc[row * 32 + 0]  = (_Float16)dxv; sc[row * 32 + 1]  = (_Float16)dyv; }
        if (g == 1) { sc[row * 32 + 10] = (_Float16)dxv; sc[row * 32 + 11] = (_Float16)dyv; }

        // L1 (body+edge): D rows0-7 = h1b, rows8-15 = h1e
        f16x8 B = *(const f16x8*)(sc + row * 32 + g * 8);
        f32x4 d = __builtin_amdgcn_mfma_f32_16x16x32_f16(A1, B, C1, 0, 0, 0);
        f16x4 t4;
        t4[0] = (_Float16)fmaxf(d.x, 0.f); t4[1] = (_Float16)fmaxf(d.y, 0.f);
        t4[2] = (_Float16)fmaxf(d.z, 0.f); t4[3] = (_Float16)fmaxf(d.w, 0.f);
        *(f16x4*)(sc + row * 32 + g * 4) = t4;              // k0-15 = [h1b|h1e]

        // L2 (body+edge): D rows0-7 = h2b, rows8-15 = h2e
        B = *(const f16x8*)(sc + row * 32 + g * 8);
        d = __builtin_amdgcn_mfma_f32_16x16x32_f16(A2, B, C2, 0, 0, 0);
        t4[0] = (_Float16)fmaxf(d.x, 0.f); t4[1] = (_Float16)fmaxf(d.y, 0.f);
        t4[2] = (_Float16)fmaxf(d.z, 0.f); t4[3] = (_Float16)fmaxf(d.w, 0.f);
        *(f16x4*)(sc + row * 32 + g * 4) = t4;              // k0-15 = [h2b|h2e]

        // hs = h2b + h2e (k0-7 valid; higher groups masked by A3 zeros; g3 aliased
        // to own zeroed k24-31 so every B slot stays finite)
        const f16x8 rA = *(const f16x8*)(sc + row * 32 + g * 8);
        const int  rbo = (g < 3) ? (row * 32 + g * 8 + 8) : (row * 32 + 24);
        const f16x8 rB = *(const f16x8*)(sc + rbo);
        B = rA + rB;
        d = __builtin_amdgcn_mfma_f32_16x16x32_f16(A3, B, C3, 0, 0, 0);
        t4[0] = (_Float16)fmaxf(d.x, 0.f); t4[1] = (_Float16)fmaxf(d.y, 0.f);
        t4[2] = (_Float16)fmaxf(d.z, 0.f); t4[3] = (_Float16)fmaxf(d.w, 0.f);
        *(f16x4*)(sc + 16 + row * 32 + g * 4) = t4;         // k16-23 = hf (k24-31 = 0)

        // Finals: B = [h2b@k0-7 | h2e@k8-15 | hf@k16-23]; rows 0/1/2 = lb/le/lf
        B = *(const f16x8*)(sc + row * 32 + g * 8);
        d = __builtin_amdgcn_mfma_f32_16x16x32_f16(A4, B, C4, 0, 0, 0);
        if (g == 0) {                                        // lanes 0-15: regs 0-2
            slogf[pxl]              = d.x;   // body logit
            slogf[TILEPX + pxl]     = d.y;   // edge logit
            slogf[2 * TILEPX + pxl] = d.z;   // fused logit
        }
    }
    __syncthreads();

    // ------- Phase 2: x2 aligned_bilinear + sigmoid + NT vf4 stores (proven R10) -------
    // item = (h, rr, q): rows y=2r+1 (A), y=2r+2 (B), cols 4q..4q+3.
    //   x=4q: (L[2q-1]+L[2q])/2  x=4q+1: L[2q]  x=4q+2: (L[2q]+L[2q+1])/2  x=4q+3: L[2q+1]
    // Row B averages tile rows rr,rr+1 (halo pre-clamped). y=0==y=1 at r==0; drop at r==99.
    for (int it = tid; it < P2ITEMS; it += 256) {
        const int h   = it / (RSTRIP * 76);
        const int rem = it - h * (RSTRIP * 76);
        const int rr  = rem / 76;
        const int q   = rem - rr * 76;
        const int r   = r0 + rr;

        const int cm = max(2 * q - 1, 0);
        const int c0 = 2 * q;
        const int cp = min(2 * q + 1, WW - 1);
        const float* L0 = slogf + h * TILEPX + rr * WW;
        const float* L1 = L0 + WW;

        const float Lm0 = L0[cm], L00 = L0[c0], Lp0 = L0[cp];
        const float Lm1 = L1[cm], L01 = L1[c0], Lp1 = L1[cp];

        const float a0 = 0.5f * (Lm0 + L00);
        const float a1 = L00;
        const float a2 = 0.5f * (L00 + Lp0);
        const float a3 = Lp0;
        const float m  = 0.5f * (Lm0 + Lm1);
        const float z  = 0.5f * (L00 + L01);
        const float pz = 0.5f * (Lp0 + Lp1);
        const float b0 = 0.5f * (m + z);
        const float b1 = z;
        const float b2 = 0.5f * (z + pz);
        const float b3 = pz;

        vf4 A, Bv;
        A.x  = 1.0f / (1.0f + __expf(-a0));
        A.y  = 1.0f / (1.0f + __expf(-a1));
        A.z  = 1.0f / (1.0f + __expf(-a2));
        A.w  = 1.0f / (1.0f + __expf(-a3));
        Bv.x = 1.0f / (1.0f + __expf(-b0));
        Bv.y = 1.0f / (1.0f + __expf(-b1));
        Bv.z = 1.0f / (1.0f + __expf(-b2));
        Bv.w = 1.0f / (1.0f + __expf(-b3));

        float* __restrict__ O = out + ((size_t)h * n_inst + n) * OUT_PER_INST;
        const int xq = 4 * q;
        __builtin_nontemporal_store(A, (vf4*)(O + (size_t)(2 * r + 1) * OWID + xq));
        if (r == 0)
            __builtin_nontemporal_store(A, (vf4*)(O + xq));
        if (r < HH - 1)
            __builtin_nontemporal_store(Bv, (vf4*)(O + (size_t)(2 * r + 2) * OWID + xq));
    }
}

extern "C" void kernel_launch(void* const* d_in, const int* in_sizes, int n_in,
                              void* d_out, int out_size, void* d_ws, size_t ws_size,
                              hipStream_t stream) {
    const float* fbody   = (const float*)d_in[0];
    const float* fedge   = (const float*)d_in[1];
    const float* params  = (const float*)d_in[2];
    const float* locs    = (const float*)d_in[3];
    const float* soi     = (const float*)d_in[4];
    const int*   im_inds = (const int*)d_in[5];
    const int*   fpn     = (const int*)d_in[6];
    // d_in[7] = mask_feat_stride (always 8; factor=2 baked into the closed form)

    const int n_inst = in_sizes[5];  // 128

    dim3 grid(NSTRIPS, n_inst);
    dmh_mfma_kernel<<<grid, dim3(256), 0, stream>>>(
        fbody, fedge, params, locs, soi, im_inds, fpn,
        (float*)d_out, n_inst);
}

// Round 13
// 49.129 us; speedup vs baseline: 1.5335x; 1.5335x over previous
//
#include <hip/hip_runtime.h>
#include <hip/hip_bf16.h>
#include <hip/hip_fp16.h>

// Problem constants (fixed by setup_inputs)
#define CIN      8
#define HH       100
#define WW       152
#define HWSZ     (HH * WW)          // 15200
#define OHGT     200
#define OWID     304
#define PPI      419                 // params per instance: 169 body + 169 edge + 81 fused
#define OUT_PER_INST (OHGT * OWID)   // 60800

#define RSTRIP   5                   // interior logit rows per block (100 = 20*5)
#define TROWS    6                   // 5 interior + 1 halo
#define NSTRIPS  20
#define QPT      38                  // quads per row (152/4)
#define P1THREADS (TROWS * QPT)      // 228 active phase-1 threads
#define P2ITEMS  (3 * RSTRIP * 76)   // 1140 upsample items per block

// Per-instance param layout (row of 419 floats):
//  body:  w1[8][10]@0  w2[8][8]@80  w3[8]@144  b1[8]@152 b2[8]@160 b3@168
//  edge:  same +169
//  fused: wf1[8][8]@338 wf2[8]@402 bf1[8]@410 bf2@418

typedef float vf4 __attribute__((ext_vector_type(4)));

// R8-proven formulation: vector w*x+a (compiler fuses + packs v_pk_fma_f32).
// R9 proved the scalarized-fmaf variant is WORSE -- do not "fix" this.
__device__ __forceinline__ vf4 fma4(float w, vf4 x, vf4 a) { return w * x + a; }
__device__ __forceinline__ vf4 relu4(vf4 x) {
    vf4 r; r.x = fmaxf(x.x, 0.f); r.y = fmaxf(x.y, 0.f);
    r.z = fmaxf(x.z, 0.f); r.w = fmaxf(x.w, 0.f); return r;
}

// ------------------------------------------------------------------------
// Fused kernel, 256 threads. Block = (instance n, 5-row strip s).
// R13 change (isolated): weights are staged once per block into LDS and read
// via ds_read broadcast (separate pipe, pipelined) instead of ~50 serialized
// s_load+lgkmcnt chains per wave through the scalar pipe.
// Phase 1: 228 threads x one 4-px quad each (R11 body otherwise unchanged).
// Phase 2: closed-form x2 aligned_bilinear + sigmoid, NT vf4 stores.
// ------------------------------------------------------------------------
__global__ __launch_bounds__(256) void dmh_fused5_kernel(
    const float* __restrict__ fbody,      // [2][8][H][W]
    const float* __restrict__ fedge,      // [2][8][H][W]
    const float* __restrict__ params,     // [n_inst][419]
    const float* __restrict__ locs,       // [n_inst][2]
    const float* __restrict__ soi_tab,    // [5]
    const int*   __restrict__ im_inds,    // [n_inst]
    const int*   __restrict__ fpn_levels, // [n_inst]
    float* __restrict__ out,              // [3][n_inst][200][304]
    int n_inst)
{
    const int s   = blockIdx.x;
    const int n   = blockIdx.y;
    const int tid = threadIdx.x;
    const int r0  = RSTRIP * s;

    __shared__ float slog[3][TROWS][WW];  // 10.9 KB
    __shared__ float wlds[PPI + 1];       // 1.7 KB: per-instance weights

    const float* __restrict__ gp = params + (size_t)n * PPI;

    // ---- Stage weights to LDS (coalesced, once per block) ----
    if (tid < PPI) wlds[tid] = gp[tid];
    if (tid + 256 < PPI) wlds[tid + 256] = gp[tid + 256];

    const int   im      = im_inds[n];
    const float inv_soi = 1.0f / soi_tab[fpn_levels[n]];
    const float sx = (locs[2 * n]     - 4.0f) * inv_soi;
    const float sy = (locs[2 * n + 1] - 4.0f) * inv_soi;
    const float k8 = 8.0f * inv_soi;

    __syncthreads();
    const float* __restrict__ p = wlds;   // all phase-1 weight reads hit LDS

    // ---------------- Phase 1: 4-px-quad dynamic MLPs -> LDS ----------------
    if (tid < P1THREADS) {
        const int rl = tid / QPT;             // 0..5
        const int c  = (tid - rl * QPT) * 4;  // 0,4,...,148
        const int r  = min(r0 + rl, HH - 1);  // halo row clamps (edge-pad)
        const int px = r * WW + c;

        const float dx0 = sx - (float)c * k8;
        const vf4 dx = { dx0, dx0 - k8, dx0 - 2.f * k8, dx0 - 3.f * k8 };
        const float dyv = sy - (float)r * k8;
        const vf4 dy = { dyv, dyv, dyv, dyv };

        const float* __restrict__ fb = fbody + (size_t)im * CIN * HWSZ + px;
        const float* __restrict__ fe = fedge + (size_t)im * CIN * HWSZ + px;

        // ---- ALL feature loads issued up front (single latency window) ----
        vf4 inb[10], ine[8];
        inb[0] = dx; inb[1] = dy;
        #pragma unroll
        for (int k = 0; k < 8; ++k)
            inb[k + 2] = *(const vf4*)(fb + k * HWSZ);   // 16B coalesced
        #pragma unroll
        for (int k = 0; k < 8; ++k)
            ine[k] = *(const vf4*)(fe + k * HWSZ);

        vf4 h1[8];

        // ---- body head ----
        #pragma unroll
        for (int o = 0; o < 8; ++o) {
            vf4 a = p[152 + o];
            #pragma unroll
            for (int k = 0; k < 10; ++k) a = fma4(p[o * 10 + k], inb[k], a);
            h1[o] = relu4(a);
        }
        vf4 h2b[8];                       // later becomes hs = h2b + h2e
        #pragma unroll
        for (int o = 0; o < 8; ++o) {
            vf4 a = p[160 + o];
            #pragma unroll
            for (int k = 0; k < 8; ++k) a = fma4(p[80 + o * 8 + k], h1[k], a);
            h2b[o] = relu4(a);
        }
        vf4 lb = p[168];
        #pragma unroll
        for (int k = 0; k < 8; ++k) lb = fma4(p[144 + k], h2b[k], lb);

        // ---- edge head (h1 regs reused; h2e never materialized as array) ----
        #pragma unroll
        for (int o = 0; o < 8; ++o) {
            vf4 a = p[169 + 152 + o];
            a = fma4(p[169 + o * 10 + 0], dx, a);
            a = fma4(p[169 + o * 10 + 1], dy, a);
            #pragma unroll
            for (int k = 0; k < 8; ++k) a = fma4(p[169 + o * 10 + 2 + k], ine[k], a);
            h1[o] = relu4(a);
        }
        vf4 le = p[169 + 168];
        #pragma unroll
        for (int o = 0; o < 8; ++o) {
            vf4 a = p[169 + 160 + o];
            #pragma unroll
            for (int k = 0; k < 8; ++k) a = fma4(p[169 + 80 + o * 8 + k], h1[k], a);
            const vf4 he = relu4(a);
            le = fma4(p[169 + 144 + o], he, le);   // incremental edge logit
            h2b[o] = h2b[o] + he;                  // hs in place
        }

        // ---- fused head on hs (= relu(h2b)+relu(h2e), in h2b regs) ----
        vf4 hf[8];
        #pragma unroll
        for (int o = 0; o < 8; ++o) {
            vf4 a = p[410 + o];
            #pragma unroll
            for (int k = 0; k < 8; ++k) a = fma4(p[338 + o * 8 + k], h2b[k], a);
            hf[o] = relu4(a);
        }
        vf4 lf = p[418];
        #pragma unroll
        for (int k = 0; k < 8; ++k) lf = fma4(p[402 + k], hf[k], lf);

        *(vf4*)&slog[0][rl][c] = lb;   // 16B-aligned LDS writes (c%4==0)
        *(vf4*)&slog[1][rl][c] = le;
        *(vf4*)&slog[2][rl][c] = lf;
    }
    __syncthreads();

    // ------- Phase 2: x2 aligned_bilinear + sigmoid + NT vf4 stores -------
    // item = (h, rr, q): output rows y=2r+1 (A), y=2r+2 (B), cols 4q..4q+3.
    //   x=4q: (L[2q-1]+L[2q])/2   x=4q+1: L[2q]
    //   x=4q+2: (L[2q]+L[2q+1])/2 x=4q+3: L[2q+1]  (cols clamped to [0,151])
    // Row B averages LDS rows rr,rr+1 (halo pre-clamped). y=0==y=1 at r==0;
    // row B dropped at r==99.
    for (int it = tid; it < P2ITEMS; it += 256) {
        const int h   = it / (RSTRIP * 76);
        const int rem = it - h * (RSTRIP * 76);
        const int rr  = rem / 76;
        const int q   = rem - rr * 76;
        const int r   = r0 + rr;

        const int cm = max(2 * q - 1, 0);
        const int c0 = 2 * q;
        const int cp = min(2 * q + 1, WW - 1);

        const float Lm0 = slog[h][rr][cm],     L00 = slog[h][rr][c0],     Lp0 = slog[h][rr][cp];
        const float Lm1 = slog[h][rr + 1][cm], L01 = slog[h][rr + 1][c0], Lp1 = slog[h][rr + 1][cp];

        // row A (y = 2r+1)
        const float a0 = 0.5f * (Lm0 + L00);
        const float a1 = L00;
        const float a2 = 0.5f * (L00 + Lp0);
        const float a3 = Lp0;
        // row B (y = 2r+2)
        const float m  = 0.5f * (Lm0 + Lm1);
        const float z  = 0.5f * (L00 + L01);
        const float pz = 0.5f * (Lp0 + Lp1);
        const float b0 = 0.5f * (m + z);
        const float b1 = z;
        const float b2 = 0.5f * (z + pz);
        const float b3 = pz;

        vf4 A, B;
        A.x = 1.0f / (1.0f + __expf(-a0));
        A.y = 1.0f / (1.0f + __expf(-a1));
        A.z = 1.0f / (1.0f + __expf(-a2));
        A.w = 1.0f / (1.0f + __expf(-a3));
        B.x = 1.0f / (1.0f + __expf(-b0));
        B.y = 1.0f / (1.0f + __expf(-b1));
        B.z = 1.0f / (1.0f + __expf(-b2));
        B.w = 1.0f / (1.0f + __expf(-b3));

        float* __restrict__ O = out + ((size_t)h * n_inst + n) * OUT_PER_INST;
        const int xq = 4 * q;
        __builtin_nontemporal_store(A, (vf4*)(O + (size_t)(2 * r + 1) * OWID + xq)); // y=2r+1
        if (r == 0)
            __builtin_nontemporal_store(A, (vf4*)(O + xq));                           // y=0 (==y=1)
        if (r < HH - 1)
            __builtin_nontemporal_store(B, (vf4*)(O + (size_t)(2 * r + 2) * OWID + xq)); // y=2r+2
    }
}

extern "C" void kernel_launch(void* const* d_in, const int* in_sizes, int n_in,
                              void* d_out, int out_size, void* d_ws, size_t ws_size,
                              hipStream_t stream) {
    const float* fbody   = (const float*)d_in[0];
    const float* fedge   = (const float*)d_in[1];
    const float* params  = (const float*)d_in[2];
    const float* locs    = (const float*)d_in[3];
    const float* soi     = (const float*)d_in[4];
    const int*   im_inds = (const int*)d_in[5];
    const int*   fpn     = (const int*)d_in[6];
    // d_in[7] = mask_feat_stride (always 8; factor=2 baked into the closed form)

    const int n_inst = in_sizes[5];  // 128

    dim3 grid(NSTRIPS, n_inst);
    dmh_fused5_kernel<<<grid, dim3(256), 0, stream>>>(
        fbody, fedge, params, locs, soi, im_inds, fpn,
        (float*)d_out, n_inst);
}

// Round 14
// 42.867 us; speedup vs baseline: 1.7575x; 1.1461x over previous
//
#include <hip/hip_runtime.h>
#include <hip/hip_bf16.h>
#include <hip/hip_fp16.h>

// Problem constants (fixed by setup_inputs)
#define CIN      8
#define HH       100
#define WW       152
#define HWSZ     (HH * WW)          // 15200
#define OHGT     200
#define OWID     304
#define PPI      419                 // params per instance: 169 body + 169 edge + 81 fused
#define OUT_PER_INST (OHGT * OWID)   // 60800

#define RSTRIP   5                   // interior logit rows per block (100 = 20*5)
#define TROWS    6                   // 5 interior + 1 halo
#define NSTRIPS  20
#define QPT      38                  // quads per row (152/4)
#define P1THREADS (TROWS * QPT)      // 228 active phase-1 threads
#define P2ITEMS  (3 * RSTRIP * 76)   // 1140 upsample items per block

// Per-instance param layout (row of 419 floats):
//  body:  w1[8][10]@0  w2[8][8]@80  w3[8]@144  b1[8]@152 b2[8]@160 b3@168
//  edge:  same +169
//  fused: wf1[8][8]@338 wf2[8]@402 bf1[8]@410 bf2@418

typedef float vf4 __attribute__((ext_vector_type(4)));

// R8-proven formulation: vector w*x+a (compiler fuses + packs v_pk_fma_f32).
// R9 proved the scalarized-fmaf variant is WORSE; R13 proved LDS-staged
// weights are WORSE (SGPR weights are free operands). Do not "fix" these.
__device__ __forceinline__ vf4 fma4(float w, vf4 x, vf4 a) { return w * x + a; }
__device__ __forceinline__ vf4 relu4(vf4 x) {
    vf4 r; r.x = fmaxf(x.x, 0.f); r.y = fmaxf(x.y, 0.f);
    r.z = fmaxf(x.z, 0.f); r.w = fmaxf(x.w, 0.f); return r;
}

// ------------------------------------------------------------------------
// Fused kernel, 256 threads. Block = (instance n, 5-row strip s).
// R14 change (isolated): __launch_bounds__(256, 4) caps VGPR at 128 ->
// guaranteed 4 waves/SIMD / 4 blocks per CU (vs est. 3 before) for
// feature-load latency cover in ph1 and cross-block ph1/ph2 overlap.
// Phase 1: 228 threads x one 4-px quad each (R11 body).
// Phase 2: closed-form x2 aligned_bilinear + sigmoid, NT vf4 stores.
// ------------------------------------------------------------------------
__global__ __launch_bounds__(256, 4) void dmh_fused6_kernel(
    const float* __restrict__ fbody,      // [2][8][H][W]
    const float* __restrict__ fedge,      // [2][8][H][W]
    const float* __restrict__ params,     // [n_inst][419]
    const float* __restrict__ locs,       // [n_inst][2]
    const float* __restrict__ soi_tab,    // [5]
    const int*   __restrict__ im_inds,    // [n_inst]
    const int*   __restrict__ fpn_levels, // [n_inst]
    float* __restrict__ out,              // [3][n_inst][200][304]
    int n_inst)
{
    const int s   = blockIdx.x;
    const int n   = blockIdx.y;
    const int tid = threadIdx.x;
    const int r0  = RSTRIP * s;

    __shared__ float slog[3][TROWS][WW];  // 10.9 KB

    const float* __restrict__ p = params + (size_t)n * PPI;
    const int   im      = im_inds[n];
    const float inv_soi = 1.0f / soi_tab[fpn_levels[n]];
    const float sx = (locs[2 * n]     - 4.0f) * inv_soi;
    const float sy = (locs[2 * n + 1] - 4.0f) * inv_soi;
    const float k8 = 8.0f * inv_soi;

    // ---------------- Phase 1: 4-px-quad dynamic MLPs -> LDS ----------------
    if (tid < P1THREADS) {
        const int rl = tid / QPT;             // 0..5
        const int c  = (tid - rl * QPT) * 4;  // 0,4,...,148
        const int r  = min(r0 + rl, HH - 1);  // halo row clamps (edge-pad)
        const int px = r * WW + c;

        const float dx0 = sx - (float)c * k8;
        const vf4 dx = { dx0, dx0 - k8, dx0 - 2.f * k8, dx0 - 3.f * k8 };
        const float dyv = sy - (float)r * k8;
        const vf4 dy = { dyv, dyv, dyv, dyv };

        const float* __restrict__ fb = fbody + (size_t)im * CIN * HWSZ + px;
        const float* __restrict__ fe = fedge + (size_t)im * CIN * HWSZ + px;

        // ---- ALL feature loads issued up front (single latency window) ----
        vf4 inb[10], ine[8];
        inb[0] = dx; inb[1] = dy;
        #pragma unroll
        for (int k = 0; k < 8; ++k)
            inb[k + 2] = *(const vf4*)(fb + k * HWSZ);   // 16B coalesced
        #pragma unroll
        for (int k = 0; k < 8; ++k)
            ine[k] = *(const vf4*)(fe + k * HWSZ);

        vf4 h1[8];

        // ---- body head ----
        #pragma unroll
        for (int o = 0; o < 8; ++o) {
            vf4 a = p[152 + o];
            #pragma unroll
            for (int k = 0; k < 10; ++k) a = fma4(p[o * 10 + k], inb[k], a);
            h1[o] = relu4(a);
        }
        vf4 h2b[8];                       // later becomes hs = h2b + h2e
        #pragma unroll
        for (int o = 0; o < 8; ++o) {
            vf4 a = p[160 + o];
            #pragma unroll
            for (int k = 0; k < 8; ++k) a = fma4(p[80 + o * 8 + k], h1[k], a);
            h2b[o] = relu4(a);
        }
        vf4 lb = p[168];
        #pragma unroll
        for (int k = 0; k < 8; ++k) lb = fma4(p[144 + k], h2b[k], lb);

        // ---- edge head (h1 regs reused; h2e never materialized as array) ----
        #pragma unroll
        for (int o = 0; o < 8; ++o) {
            vf4 a = p[169 + 152 + o];
            a = fma4(p[169 + o * 10 + 0], dx, a);
            a = fma4(p[169 + o * 10 + 1], dy, a);
            #pragma unroll
            for (int k = 0; k < 8; ++k) a = fma4(p[169 + o * 10 + 2 + k], ine[k], a);
            h1[o] = relu4(a);
        }
        vf4 le = p[169 + 168];
        #pragma unroll
        for (int o = 0; o < 8; ++o) {
            vf4 a = p[169 + 160 + o];
            #pragma unroll
            for (int k = 0; k < 8; ++k) a = fma4(p[169 + 80 + o * 8 + k], h1[k], a);
            const vf4 he = relu4(a);
            le = fma4(p[169 + 144 + o], he, le);   // incremental edge logit
            h2b[o] = h2b[o] + he;                  // hs in place
        }

        // ---- fused head on hs (= relu(h2b)+relu(h2e), in h2b regs) ----
        vf4 hf[8];
        #pragma unroll
        for (int o = 0; o < 8; ++o) {
            vf4 a = p[410 + o];
            #pragma unroll
            for (int k = 0; k < 8; ++k) a = fma4(p[338 + o * 8 + k], h2b[k], a);
            hf[o] = relu4(a);
        }
        vf4 lf = p[418];
        #pragma unroll
        for (int k = 0; k < 8; ++k) lf = fma4(p[402 + k], hf[k], lf);

        *(vf4*)&slog[0][rl][c] = lb;   // 16B-aligned LDS writes (c%4==0)
        *(vf4*)&slog[1][rl][c] = le;
        *(vf4*)&slog[2][rl][c] = lf;
    }
    __syncthreads();

    // ------- Phase 2: x2 aligned_bilinear + sigmoid + NT vf4 stores -------
    // item = (h, rr, q): output rows y=2r+1 (A), y=2r+2 (B), cols 4q..4q+3.
    //   x=4q: (L[2q-1]+L[2q])/2   x=4q+1: L[2q]
    //   x=4q+2: (L[2q]+L[2q+1])/2 x=4q+3: L[2q+1]  (cols clamped to [0,151])
    // Row B averages LDS rows rr,rr+1 (halo pre-clamped). y=0==y=1 at r==0;
    // row B dropped at r==99.
    for (int it = tid; it < P2ITEMS; it += 256) {
        const int h   = it / (RSTRIP * 76);
        const int rem = it - h * (RSTRIP * 76);
        const int rr  = rem / 76;
        const int q   = rem - rr * 76;
        const int r   = r0 + rr;

        const int cm = max(2 * q - 1, 0);
        const int c0 = 2 * q;
        const int cp = min(2 * q + 1, WW - 1);

        const float Lm0 = slog[h][rr][cm],     L00 = slog[h][rr][c0],     Lp0 = slog[h][rr][cp];
        const float Lm1 = slog[h][rr + 1][cm], L01 = slog[h][rr + 1][c0], Lp1 = slog[h][rr + 1][cp];

        // row A (y = 2r+1)
        const float a0 = 0.5f * (Lm0 + L00);
        const float a1 = L00;
        const float a2 = 0.5f * (L00 + Lp0);
        const float a3 = Lp0;
        // row B (y = 2r+2)
        const float m  = 0.5f * (Lm0 + Lm1);
        const float z  = 0.5f * (L00 + L01);
        const float pz = 0.5f * (Lp0 + Lp1);
        const float b0 = 0.5f * (m + z);
        const float b1 = z;
        const float b2 = 0.5f * (z + pz);
        const float b3 = pz;

        vf4 A, B;
        A.x = 1.0f / (1.0f + __expf(-a0));
        A.y = 1.0f / (1.0f + __expf(-a1));
        A.z = 1.0f / (1.0f + __expf(-a2));
        A.w = 1.0f / (1.0f + __expf(-a3));
        B.x = 1.0f / (1.0f + __expf(-b0));
        B.y = 1.0f / (1.0f + __expf(-b1));
        B.z = 1.0f / (1.0f + __expf(-b2));
        B.w = 1.0f / (1.0f + __expf(-b3));

        float* __restrict__ O = out + ((size_t)h * n_inst + n) * OUT_PER_INST;
        const int xq = 4 * q;
        __builtin_nontemporal_store(A, (vf4*)(O + (size_t)(2 * r + 1) * OWID + xq)); // y=2r+1
        if (r == 0)
            __builtin_nontemporal_store(A, (vf4*)(O + xq));                           // y=0 (==y=1)
        if (r < HH - 1)
            __builtin_nontemporal_store(B, (vf4*)(O + (size_t)(2 * r + 2) * OWID + xq)); // y=2r+2
    }
}

extern "C" void kernel_launch(void* const* d_in, const int* in_sizes, int n_in,
                              void* d_out, int out_size, void* d_ws, size_t ws_size,
                              hipStream_t stream) {
    const float* fbody   = (const float*)d_in[0];
    const float* fedge   = (const float*)d_in[1];
    const float* params  = (const float*)d_in[2];
    const float* locs    = (const float*)d_in[3];
    const float* soi     = (const float*)d_in[4];
    const int*   im_inds = (const int*)d_in[5];
    const int*   fpn     = (const int*)d_in[6];
    // d_in[7] = mask_feat_stride (always 8; factor=2 baked into the closed form)

    const int n_inst = in_sizes[5];  // 128

    dim3 grid(NSTRIPS, n_inst);
    dmh_fused6_kernel<<<grid, dim3(256), 0, stream>>>(
        fbody, fedge, params, locs, soi, im_inds, fpn,
        (float*)d_out, n_inst);
}